// Round 1
// baseline (46.842 us; speedup 1.0000x reference)
//
#include <hip/hip_runtime.h>
#include <float.h>

#define GDIM 12
#define NC   144          // GDIM*GDIM
#define FINF 1.0e9f

// 8-connected neighborhood, same order as the reference DIRS
__device__ __constant__ int DI8[8] = {-1, -1, -1, 0, 0, 1, 1, 1};
__device__ __constant__ int DJ8[8] = {-1,  0,  1,-1, 1,-1, 0, 1};

__global__ __launch_bounds__(64)
void path_kernel(const int* __restrict__ w,
                 const float* __restrict__ costs,
                 int* __restrict__ out) {
    const int k = blockIdx.x;     // problem id
    const int l = threadIdx.x;    // lane 0..63

    __shared__ float dist[NC + 1];   // +1 sentinel slot = FINF for OOB neighbors
    __shared__ float cost[NC];
    __shared__ int   mask[NC];

    const int* wk = w + (size_t)k * NC;

    // ---- init: gather costs, dist=INF, mask=0 ----
    for (int c = l; c < NC; c += 64) {
        cost[c] = costs[wk[c]];
        dist[c] = FINF;
        mask[c] = 0;
    }
    if (l == 0) dist[NC] = FINF;
    __syncthreads();
    if (l == 0) dist[0] = cost[0];
    __syncthreads();

    // ---- precompute per-lane cells and neighbor indices ----
    // lane l owns cells l, l+64, l+128(if <144)
    int   nb[3][8];
    float cc[3];
    #pragma unroll
    for (int m = 0; m < 3; ++m) {
        int c = l + 64 * m;
        if (c < NC) {
            int i = c / GDIM, j = c - (c / GDIM) * GDIM;
            cc[m] = cost[c];
            #pragma unroll
            for (int d = 0; d < 8; ++d) {
                int ii = i + DI8[d], jj = j + DJ8[d];
                bool valid = (ii >= 0) & (ii < GDIM) & (jj >= 0) & (jj < GDIM);
                nb[m][d] = valid ? (ii * GDIM + jj) : NC;   // NC -> sentinel INF
            }
        }
    }

    // ---- relax to fixed point (monotone, converges to same f32 values
    //      as the reference's 144 synchronous sweeps) ----
    for (int it = 0; it < NC; ++it) {
        bool changed = false;
        #pragma unroll
        for (int m = 0; m < 3; ++m) {
            int c = l + 64 * m;
            if (c < NC) {
                float mn = dist[nb[m][0]];
                #pragma unroll
                for (int d = 1; d < 8; ++d) mn = fminf(mn, dist[nb[m][d]]);
                float cur = dist[c];
                float nv  = fminf(cur, cc[m] + mn);
                if (nv < cur) { dist[c] = nv; changed = true; }
            }
        }
        __syncthreads();
        if (__ballot(changed) == 0ull) break;   // uniform across the wave
    }

    // ---- backtrack on lane 0 (argmin-first-occurrence over DIRS order) ----
    if (l == 0) {
        int pi = GDIM - 1, pj = GDIM - 1;
        mask[pi * GDIM + pj] = 1;
        for (int s = 0; s < NC; ++s) {
            if (pi == 0 && pj == 0) break;
            float best = FLT_MAX;
            int bi = pi, bj = pj;
            #pragma unroll
            for (int d = 0; d < 8; ++d) {
                int ci = pi + DI8[d], cj = pj + DJ8[d];
                bool valid = (ci >= 0) & (ci < GDIM) & (cj >= 0) & (cj < GDIM);
                int cic = min(max(ci, 0), GDIM - 1);
                int cjc = min(max(cj, 0), GDIM - 1);
                float v = valid ? dist[cic * GDIM + cjc] : FINF;
                if (v < best) { best = v; bi = cic; bj = cjc; }   // first-wins tie
            }
            pi = bi; pj = bj;
            mask[pi * GDIM + pj] = 1;
        }
    }
    __syncthreads();

    // ---- coalesced store of the 0/1 mask (writes every output element) ----
    int* outk = out + (size_t)k * NC;
    for (int c = l; c < NC; c += 64) outk[c] = mask[c];
}

extern "C" void kernel_launch(void* const* d_in, const int* in_sizes, int n_in,
                              void* d_out, int out_size, void* d_ws, size_t ws_size,
                              hipStream_t stream) {
    const int*   w     = (const int*)d_in[0];
    const float* costs = (const float*)d_in[1];
    int*         out   = (int*)d_out;
    const int K = in_sizes[0] / NC;   // 8192 problems
    path_kernel<<<dim3(K), dim3(64), 0, stream>>>(w, costs, out);
}

// Round 2
// 25.281 us; speedup vs baseline: 1.8529x; 1.8529x over previous
//
#include <hip/hip_runtime.h>
#include <float.h>

#define GDIM 12
#define NC   144          // GDIM*GDIM
#define FINF 1.0e9f

// 8-connected neighborhood, same order as the reference DIRS
__device__ __constant__ int DI8[8] = {-1, -1, -1, 0, 0, 1, 1, 1};
__device__ __constant__ int DJ8[8] = {-1,  0,  1,-1, 1,-1, 0, 1};

// DPP shift within 16-lane rows; invalid source lanes keep `old` = INF.
__device__ inline float dpp_shr1(float x) {
    return __int_as_float(__builtin_amdgcn_update_dpp(
        __float_as_int(FINF), __float_as_int(x), 0x111, 0xf, 0xf, false));
}
__device__ inline float dpp_shl1(float x) {
    return __int_as_float(__builtin_amdgcn_update_dpp(
        __float_as_int(FINF), __float_as_int(x), 0x101, 0xf, 0xf, false));
}

// One row-relaxation for row i (compile-time i via full unroll).
// min(L,R) is symmetric, so DPP direction convention doesn't matter;
// boundaries (j==0, j==11) are guarded by bound_ctrl-INF and idle lanes 12..15.
#define ROWUPD(i) {                                                  \
    float dm1 = ((i) > 0)        ? d[(i)-1] : FINF;                  \
    float dp1 = ((i) < GDIM - 1) ? d[(i)+1] : FINF;                  \
    float V   = fminf(dm1, dp1);                                     \
    float cm3 = fminf(V, d[(i)]);                                    \
    float L   = dpp_shr1(cm3);                                       \
    float R   = dpp_shl1(cm3);                                       \
    float nbr = fminf(fminf(L, R), V);                               \
    float nd  = c[(i)] + nbr;                                        \
    if (nd < d[(i)]) { d[(i)] = nd; changed = true; } }

__global__ __launch_bounds__(64)
void path_kernel(const int* __restrict__ w,
                 const float* __restrict__ costs,
                 int* __restrict__ out) {
    const int l = threadIdx.x;      // lane 0..63
    const int g = l >> 4;           // problem group 0..3 within the wave
    const int j = l & 15;           // column (0..11 active, 12..15 idle=INF)
    const int pbase = blockIdx.x * 4;

    __shared__ int   s_w[4 * NC];
    __shared__ float dl[4][NC];
    __shared__ int   ml[4 * NC];

    // coalesced staging of 4 problems' weights + mask init
    const int* wblk = w + (size_t)pbase * NC;
    #pragma unroll
    for (int t = 0; t < 9; ++t) { s_w[t * 64 + l] = wblk[t * 64 + l]; ml[t * 64 + l] = 0; }
    __syncthreads();

    // per-lane column state: d[i] = dist(i, j), c[i] = cost(i, j)
    const bool act = (j < GDIM);
    float c[GDIM], d[GDIM];
    #pragma unroll
    for (int i = 0; i < GDIM; ++i) {
        c[i] = act ? costs[s_w[g * NC + i * GDIM + j]] : FINF;
        d[i] = FINF;
    }
    if (j == 0) d[0] = c[0];        // source cell (0,0)

    // alternating-direction Gauss-Seidel sweeps, all in registers + DPP.
    // Monotone relaxation -> same f32 fixed point as the reference's
    // 144 synchronous sweeps (every value is a path-fold sum; min is exact).
    for (int it = 0; it < 200; ++it) {
        bool changed = false;
        if ((it & 1) == 0) {
            #pragma unroll
            for (int i = 0; i < GDIM; ++i) ROWUPD(i)
        } else {
            #pragma unroll
            for (int ii = 0; ii < GDIM; ++ii) { const int i = GDIM - 1 - ii; ROWUPD(i) }
        }
        if (__ballot(changed) == 0ull) break;
    }

    // dump dist to LDS for the backtrack
    if (act) {
        #pragma unroll
        for (int i = 0; i < GDIM; ++i) dl[g][i * GDIM + j] = d[i];
    }
    __syncthreads();

    // backtrack: lanes 0/16/32/48 walk their own problem simultaneously.
    // argmin-first-occurrence over DIRS order, strict-<, clipped coords.
    {
        const bool lead = (j == 0);
        int pi = GDIM - 1, pj = GDIM - 1;
        if (lead) ml[g * NC + NC - 1] = 1;
        bool walking = lead;
        for (int s = 0; s < NC; ++s) {
            if (__ballot(walking) == 0ull) break;
            if (walking) {
                if (pi == 0 && pj == 0) walking = false;
                else {
                    float best = FLT_MAX; int bi = pi, bj = pj;
                    #pragma unroll
                    for (int dd = 0; dd < 8; ++dd) {
                        int ci = pi + DI8[dd], cj = pj + DJ8[dd];
                        bool valid = (ci >= 0) & (ci < GDIM) & (cj >= 0) & (cj < GDIM);
                        int cic = min(max(ci, 0), GDIM - 1);
                        int cjc = min(max(cj, 0), GDIM - 1);
                        float v = valid ? dl[g][cic * GDIM + cjc] : FINF;
                        if (v < best) { best = v; bi = cic; bj = cjc; }  // first-wins tie
                    }
                    pi = bi; pj = bj;
                    ml[g * NC + pi * GDIM + pj] = 1;
                }
            }
        }
    }
    __syncthreads();

    // coalesced store (writes every output element; no stale state)
    int* outblk = out + (size_t)pbase * NC;
    #pragma unroll
    for (int t = 0; t < 9; ++t) outblk[t * 64 + l] = ml[t * 64 + l];
}

extern "C" void kernel_launch(void* const* d_in, const int* in_sizes, int n_in,
                              void* d_out, int out_size, void* d_ws, size_t ws_size,
                              hipStream_t stream) {
    const int*   w     = (const int*)d_in[0];
    const float* costs = (const float*)d_in[1];
    int*         out   = (int*)d_out;
    const int K = in_sizes[0] / NC;          // 8192 problems
    path_kernel<<<dim3(K / 4), dim3(64), 0, stream>>>(w, costs, out);
}

// Round 3
// 24.428 us; speedup vs baseline: 1.9176x; 1.0349x over previous
//
#include <hip/hip_runtime.h>
#include <float.h>

#define GDIM 12
#define NC   144          // GDIM*GDIM
#define FINF 1.0e9f

// Rotate within 16-lane DPP rows. Idle lanes 12..15 hold FINF, so the
// wrap-around value IS the out-of-bounds guard; min(L,R) symmetry makes
// the rotation direction convention irrelevant.
__device__ inline float rotA(float x) {   // row_ror:1
    return __int_as_float(__builtin_amdgcn_update_dpp(
        __float_as_int(x), __float_as_int(x), 0x121, 0xf, 0xf, false));
}
__device__ inline float rotB(float x) {   // row_ror:15
    return __int_as_float(__builtin_amdgcn_update_dpp(
        __float_as_int(x), __float_as_int(x), 0x12F, 0xf, 0xf, false));
}

// One row relaxation (compile-time i). Exact reference expression form:
// nd = c + min(8 neighbors); d = min(d, nd). TRACK adds convergence check.
#define ROWU(i, TRACK) {                                                   \
    float dm1 = ((i) > 0)        ? d[(i)-1] : FINF;                        \
    float dp1 = ((i) < GDIM - 1) ? d[(i)+1] : FINF;                       \
    float V   = fminf(dm1, dp1);                                           \
    float cm3 = fminf(V, d[(i)]);                                          \
    float nbr = fminf(fminf(rotA(cm3), rotB(cm3)), V);                     \
    float nd  = c[(i)] + nbr;                                              \
    if (TRACK) changed = changed | (nd < d[(i)]);                          \
    d[(i)] = fminf(d[(i)], nd); }

// Red-black sweep: even rows (depend only on odd), then odd rows.
// 6 independent row-chains per half-sweep -> 6-way ILP.
#define RB_SWEEP(TRACK) {                                                  \
    _Pragma("unroll")                                                      \
    for (int i = 0; i < GDIM; i += 2) ROWU(i, TRACK)                       \
    _Pragma("unroll")                                                      \
    for (int i = 1; i < GDIM; i += 2) ROWU(i, TRACK)                       \
}

// Padded 14x14 neighbor offsets in exact reference DIRS order.
__device__ __constant__ int POFF[8] = {-15, -14, -13, -1, 1, 13, 14, 15};

__global__ __launch_bounds__(64)
void path_kernel(const int* __restrict__ w,
                 const float* __restrict__ costs,
                 int* __restrict__ out) {
    const int l = threadIdx.x;      // lane 0..63
    const int g = l >> 4;           // problem group 0..3 within the wave
    const int j = l & 15;           // column (0..11 active, 12..15 idle=INF)
    const int pbase = blockIdx.x * 4;

    __shared__ int   s_w[4 * NC];
    __shared__ float dl[4][196];    // 14x14 padded dist, border = INF
    __shared__ int   ml[4 * NC];

    // coalesced staging of 4 problems' weights; zero masks; INF-fill dl
    const int* wblk = w + (size_t)pbase * NC;
    #pragma unroll
    for (int t = 0; t < 9; ++t) { s_w[t * 64 + l] = wblk[t * 64 + l]; ml[t * 64 + l] = 0; }
    {
        float* dlf = &dl[0][0];
        #pragma unroll
        for (int t = 0; t < 13; ++t) { int idx = t * 64 + l; if (idx < 784) dlf[idx] = FINF; }
    }
    __syncthreads();

    // per-lane column state: d[i] = dist(i, j), c[i] = cost(i, j)
    const bool act = (j < GDIM);
    float c[GDIM], d[GDIM];
    #pragma unroll
    for (int i = 0; i < GDIM; ++i) {
        c[i] = act ? costs[s_w[g * NC + i * GDIM + j]] : FINF;
        d[i] = FINF;
    }
    if (j == 0) d[0] = c[0];        // source cell (0,0)

    // red-black relaxation to fixed point; ballot-check every 2nd sweep.
    // Monotone chaotic relaxation from INF -> same f32 fixed point as the
    // reference's 144 synchronous sweeps (identical per-update expressions).
    for (int pair = 0; pair < 80; ++pair) {
        bool changed = false;
        RB_SWEEP(false)
        RB_SWEEP(true)
        if (__ballot(changed) == 0ull) break;
    }

    // dump dist into padded LDS interior
    if (act) {
        #pragma unroll
        for (int i = 0; i < GDIM; ++i) dl[g][(i + 1) * 14 + (j + 1)] = d[i];
    }
    __syncthreads();

    // backtrack: 4 walkers (lanes 0/16/32/48) in parallel. INF border makes
    // every neighbor read in-bounds; first-wins strict-< scan in DIRS order
    // == reference argmin over (valid ? dist : INF).
    if (j == 0) {
        int a = 12 * 14 + 12;                 // padded addr of (11,11)
        ml[g * NC + NC - 1] = 1;
        int guard = 0;
        while (a != (1 * 14 + 1) && guard < 200) {
            ++guard;
            float best = FLT_MAX; int ba = a;
            #pragma unroll
            for (int dd = 0; dd < 8; ++dd) {
                int na = a + POFF[dd];
                float v = dl[g][na];
                if (v < best) { best = v; ba = na; }   // first-wins tie
            }
            a = ba;
            int ii = a / 14 - 1, jj = a % 14 - 1;
            ml[g * NC + ii * GDIM + jj] = 1;
        }
    }
    __syncthreads();

    // coalesced store (writes every output element; no stale state)
    int* outblk = out + (size_t)pbase * NC;
    #pragma unroll
    for (int t = 0; t < 9; ++t) outblk[t * 64 + l] = ml[t * 64 + l];
}

extern "C" void kernel_launch(void* const* d_in, const int* in_sizes, int n_in,
                              void* d_out, int out_size, void* d_ws, size_t ws_size,
                              hipStream_t stream) {
    const int*   w     = (const int*)d_in[0];
    const float* costs = (const float*)d_in[1];
    int*         out   = (int*)d_out;
    const int K = in_sizes[0] / NC;          // 8192 problems
    path_kernel<<<dim3(K / 4), dim3(64), 0, stream>>>(w, costs, out);
}